// Round 2
// baseline (148.594 us; speedup 1.0000x reference)
//
#include <hip/hip_runtime.h>

#define N_BOND   100000
#define D_DIM    192
#define N_ETYPES 36
#define E_PER_TYPE 30000
#define BATCH    256
#define TOTAL_E  (N_ETYPES * E_PER_TYPE)
#define EPT      8   // edges per thread in edge_kernel (30000 % 8 == 0)

// Kernel 1: hv[n] = dot(h[n,:], W). One 64-lane wave per row; each lane loads
// 3 dwords at lane, lane+64, lane+128 (three coalesced 256B segments/wave,
// all 64 lanes active), then 6-step shuffle reduce. Also zero-inits acc[] so
// no separate memset dispatch is needed (same-stream ordering before edge_kernel).
__global__ void hv_kernel(const float* __restrict__ h, const float* __restrict__ W,
                          float* __restrict__ hv, float* __restrict__ acc) {
    int gid  = blockIdx.x * blockDim.x + threadIdx.x;
    if (gid < N_ETYPES * BATCH) acc[gid] = 0.f;
    int row  = gid >> 6;
    int lane = threadIdx.x & 63;
    if (row >= N_BOND) return;
    const float* hr = h + (size_t)row * D_DIM;
    float v = hr[lane]       * W[lane]
            + hr[lane + 64]  * W[lane + 64]
            + hr[lane + 128] * W[lane + 128];
#pragma unroll
    for (int d = 32; d > 0; d >>= 1) v += __shfl_down(v, d, 64);
    if (lane == 0) hv[row] = v;
}

// Kernel 2: scalar segment-sum. Each thread handles 8 consecutive edges
// (int4 x2 index loads, fully coalesced). Keys t*BATCH+seg are sorted, avg
// run length ~32, so serial run-compaction emits ~1.25 atomics/thread
// (~170k fire-and-forget f32 atomics over 9216 addresses).
__global__ void edge_kernel(const int* __restrict__ edge_src,
                            const int* __restrict__ edge_seg,
                            const float* __restrict__ hv,
                            float* __restrict__ acc) {
    int tid  = blockIdx.x * blockDim.x + threadIdx.x;
    int base = tid * EPT;
    if (base >= TOTAL_E) return;
    int t = base / E_PER_TYPE;          // constant within the 8-pack (30000 % 8 == 0)
    const int4* sp = (const int4*)(edge_src + base);
    const int4* gp = (const int4*)(edge_seg + base);
    int4 s0 = sp[0], s1 = sp[1];
    int4 g0 = gp[0], g1 = gp[1];
    int srcs[EPT] = {s0.x, s0.y, s0.z, s0.w, s1.x, s1.y, s1.z, s1.w};
    int segs[EPT] = {g0.x, g0.y, g0.z, g0.w, g1.x, g1.y, g1.z, g1.w};
    float vals[EPT];
#pragma unroll
    for (int j = 0; j < EPT; ++j) vals[j] = hv[srcs[j]];   // L2-resident gathers (hv = 400 KB)
    int tb  = t * BATCH;
    float run = vals[0];
    int   rk  = tb + segs[0];
#pragma unroll
    for (int j = 1; j < EPT; ++j) {
        int k = tb + segs[j];
        if (k == rk) { run += vals[j]; }
        else { atomicAdd(&acc[rk], run); rk = k; run = vals[j]; }
    }
    atomicAdd(&acc[rk], run);
}

// Kernel 3: mask + softmax over 36 types per graph. Thread b handles graph b;
// acc reads coalesced (acc[t*BATCH+b]). Mask storage width auto-detected
// (bool-1B vs int32): int32 storage has every word exactly 0/1.
__global__ void softmax_kernel(const float* __restrict__ acc,
                               const void* __restrict__ mask,
                               float* __restrict__ out) {
    int b = threadIdx.x;  // 256 threads, 1 block

    const unsigned int* mi = (const unsigned int*)mask;
    bool is_u8 = false;
#pragma unroll
    for (int i = 0; i < 16; ++i) is_u8 |= (mi[i] > 1u);
    const unsigned char* m8  = (const unsigned char*)mask;
    const int*           m32 = (const int*)mask;

    float v[N_ETYPES];
    float mx = -1e30f;
#pragma unroll
    for (int t = 0; t < N_ETYPES; ++t) {
        float x = acc[t * BATCH + b];
        bool masked = is_u8 ? (m8[b * N_ETYPES + t] != 0)
                            : (m32[b * N_ETYPES + t] != 0);
        x = masked ? -1e9f : x;
        v[t] = x;
        mx = fmaxf(mx, x);
    }
    float s = 0.f;
#pragma unroll
    for (int t = 0; t < N_ETYPES; ++t) { v[t] = expf(v[t] - mx); s += v[t]; }
    float inv = 1.f / s;
#pragma unroll
    for (int t = 0; t < N_ETYPES; ++t) out[b * N_ETYPES + t] = v[t] * inv;
}

extern "C" void kernel_launch(void* const* d_in, const int* in_sizes, int n_in,
                              void* d_out, int out_size, void* d_ws, size_t ws_size,
                              hipStream_t stream) {
    const float* h        = (const float*)d_in[0];   // [100000, 192]
    const float* W        = (const float*)d_in[1];   // [192, 1]
    const int*   edge_src = (const int*)d_in[2];     // [36, 30000]
    const int*   edge_seg = (const int*)d_in[3];     // [36, 30000]
    const void*  mask     = d_in[4];                 // [256, 36] bool (width auto-detected)
    float*       out      = (float*)d_out;           // [256, 36]

    float* hv  = (float*)d_ws;                       // 100000 floats
    float* acc = (float*)((char*)d_ws + 400128);     // 9216 floats, 128B-aligned

    // hv_kernel also zero-inits acc (gid < 9216) — no memset dispatch.
    hipLaunchKernelGGL(hv_kernel, dim3((N_BOND + 3) / 4), dim3(256), 0, stream,
                       h, W, hv, acc);

    int nthreads = TOTAL_E / EPT;                    // 135000
    hipLaunchKernelGGL(edge_kernel, dim3((nthreads + 255) / 256), dim3(256), 0, stream,
                       edge_src, edge_seg, hv, acc);

    hipLaunchKernelGGL(softmax_kernel, dim3(1), dim3(256), 0, stream, acc, mask, out);
}